// Round 5
// baseline (607.861 us; speedup 1.0000x reference)
//
#include <hip/hip_runtime.h>
#include <hip/hip_fp16.h>
#include <math.h>

// GCN 3-layer: h = relu(Agg(x@W1)+b1); h = relu(Agg(h@W2)+b2); out = Agg(h@W3)+b3
// Agg[i] = dinv[i]^2 * g[i] + sum_{e: dst=i} dinv[src]*dinv[i] * g[src]
// dinv = rsqrt(in_deg + 1)
// GEMMs run on MFMA with fp16 hi/lo split (3 products: XhWh + XlWh + XhWl)
// -> f32-level accuracy at matrix-core rate. Activations stored fp16 for the
// gather phase; aggregation accumulates f32.

#define N_NODES 100000
#define N_EDGES 1600000

typedef _Float16 f16x8 __attribute__((ext_vector_type(8)));
typedef float    f32x4 __attribute__((ext_vector_type(4)));

// ---------------- preprocessing ----------------

__global__ __launch_bounds__(256) void k_zero_int(int* __restrict__ p, int n) {
    int i = blockIdx.x * 256 + threadIdx.x;
    if (i < n) p[i] = 0;
}

__global__ __launch_bounds__(256) void k_count(const int* __restrict__ dst, int* __restrict__ cnt, int E) {
    int e = blockIdx.x * 256 + threadIdx.x;
    if (e < E) atomicAdd(&cnt[dst[e]], 1);
}

// per-256-block exclusive scan (over 8-padded counts) + block sums
__global__ __launch_bounds__(256) void k_scan_block(const int* __restrict__ cnt, int* __restrict__ excl,
                                                    int* __restrict__ bsum, int n) {
    __shared__ int s[256];
    int i = blockIdx.x * 256 + threadIdx.x;
    int v = (i < n) ? ((cnt[i] + 7) & ~7) : 0;   // padded segment length
    s[threadIdx.x] = v;
    __syncthreads();
    #pragma unroll
    for (int off = 1; off < 256; off <<= 1) {
        int t = (threadIdx.x >= (unsigned)off) ? s[threadIdx.x - off] : 0;
        __syncthreads();
        s[threadIdx.x] += t;
        __syncthreads();
    }
    if (i < n) excl[i] = s[threadIdx.x] - v;
    if (threadIdx.x == 255) bsum[blockIdx.x] = s[255];
}

// single-block exclusive scan over block sums (nb <= 512)
__global__ __launch_bounds__(512) void k_scan_partials(int* __restrict__ bsum, int nb) {
    __shared__ int s[512];
    int tid = threadIdx.x;
    int v = (tid < nb) ? bsum[tid] : 0;
    s[tid] = v;
    __syncthreads();
    #pragma unroll
    for (int off = 1; off < 512; off <<= 1) {
        int t = (tid >= (unsigned)off) ? s[tid - off] : 0;
        __syncthreads();
        s[tid] += t;
        __syncthreads();
    }
    if (tid < nb) bsum[tid] = s[tid] - v;   // exclusive
}

__global__ __launch_bounds__(256) void k_finalize(const int* __restrict__ excl, const int* __restrict__ bsum,
                                                  const int* __restrict__ cnt, int* __restrict__ rowptr,
                                                  int* __restrict__ fill, float* __restrict__ dinv, int n) {
    int i = blockIdx.x * 256 + threadIdx.x;
    if (i < n) {
        int rp = excl[i] + bsum[i >> 8];
        rowptr[i] = rp;     // 8-aligned
        fill[i]   = rp;
        dinv[i]   = rsqrtf((float)(cnt[i] + 1));
    }
}

__global__ __launch_bounds__(256) void k_zero_csr(int2* __restrict__ csr, int n) {
    int i = blockIdx.x * 256 + threadIdx.x;
    if (i < n) csr[i] = make_int2(0, 0);
}

__global__ __launch_bounds__(256) void k_fill_edges(const int* __restrict__ src, const int* __restrict__ dst,
                                                    const float* __restrict__ dinv, int* __restrict__ fill,
                                                    int2* __restrict__ csr, int E) {
    int e = blockIdx.x * 256 + threadIdx.x;
    if (e < E) {
        int s = src[e], d = dst[e];
        int p = atomicAdd(&fill[d], 1);
        csr[p] = make_int2(s, __float_as_int(dinv[s] * dinv[d]));
    }
}

// W split+transpose: WT_h[c][k] = fp16(W[k][c]); WT_l = fp16(residual). [K*128 threads]
__global__ __launch_bounds__(256) void k_wsplit(const float* __restrict__ W, _Float16* __restrict__ WTh,
                                                _Float16* __restrict__ WTl, int K) {
    int i = blockIdx.x * 256 + threadIdx.x;
    if (i < K * 128) {
        int k = i >> 7, c = i & 127;
        float w = W[(size_t)k * 128 + c];
        _Float16 h = (_Float16)w;
        WTh[(size_t)c * K + k] = h;
        WTl[(size_t)c * K + k] = (_Float16)(w - (float)h);
    }
}

// ---------------- MFMA GEMM: Y[n,128] = X[n,K] @ W[K,128], fp16 out ----------------
// 4 waves/block, each wave owns 16 rows x 128 cols. No LDS, no barriers.
// A: f32 X rows split to fp16 hi/lo in registers. B: pre-split WT_h/WT_l [128][K].
// Fragment maps (guide §3, m89-verified): A row=lane&15, k=(lane>>4)*8+i;
// B col=lane&15, same k; D col=lane&15, row=(lane>>4)*4+reg.

template <int K>
__global__ __launch_bounds__(256) void k_gemm_mfma(const float* __restrict__ X,
                                                   const _Float16* __restrict__ WTh,
                                                   const _Float16* __restrict__ WTl,
                                                   _Float16* __restrict__ Y, int n) {
    const int t    = threadIdx.x;
    const int wave = t >> 6;
    const int lane = t & 63;
    const int lrow = lane & 15;
    const int kgrp = lane >> 4;          // 0..3
    const int row0 = blockIdx.x * 64 + wave * 16;
    const int arow = row0 + lrow;
    const bool rok = arow < n;
    const float* __restrict__ xrow = X + (size_t)arow * K;

    f32x4 acc[8];
    #pragma unroll
    for (int i = 0; i < 8; ++i) acc[i] = (f32x4){0.f, 0.f, 0.f, 0.f};

    const _Float16* __restrict__ bh0 = WTh + (size_t)lrow * K;
    const _Float16* __restrict__ bl0 = WTl + (size_t)lrow * K;

    for (int kb = 0; kb < K; kb += 32) {
        const int k0 = kb + kgrp * 8;
        float4 x0 = make_float4(0.f, 0.f, 0.f, 0.f);
        float4 x1 = make_float4(0.f, 0.f, 0.f, 0.f);
        if (rok) {
            x0 = *(const float4*)&xrow[k0];
            x1 = *(const float4*)&xrow[k0 + 4];
        }
        float xs[8] = {x0.x, x0.y, x0.z, x0.w, x1.x, x1.y, x1.z, x1.w};
        f16x8 ah, al;
        #pragma unroll
        for (int i = 0; i < 8; ++i) {
            _Float16 h = (_Float16)xs[i];
            ah[i] = h;
            al[i] = (_Float16)(xs[i] - (float)h);
        }
        #pragma unroll
        for (int tc = 0; tc < 8; ++tc) {
            f16x8 bh = *(const f16x8*)(bh0 + (size_t)tc * 16 * K + k0);
            f16x8 bl = *(const f16x8*)(bl0 + (size_t)tc * 16 * K + k0);
            acc[tc] = __builtin_amdgcn_mfma_f32_16x16x32_f16(ah, bh, acc[tc], 0, 0, 0);
            acc[tc] = __builtin_amdgcn_mfma_f32_16x16x32_f16(al, bh, acc[tc], 0, 0, 0);
            acc[tc] = __builtin_amdgcn_mfma_f32_16x16x32_f16(ah, bl, acc[tc], 0, 0, 0);
        }
    }

    #pragma unroll
    for (int r = 0; r < 4; ++r) {
        int grow = row0 + kgrp * 4 + r;
        if (grow < n) {
            _Float16* yr = Y + (size_t)grow * 128 + lrow;
            #pragma unroll
            for (int tc = 0; tc < 8; ++tc) yr[tc * 16] = (_Float16)acc[tc][r];
        }
    }
}

// ---------------- aggregation (+ bias, + optional relu) ----------------
// one wave per node, grid-stride; lane holds 2 features (uint = 2 halves).
// CSR 8-padded, interleaved (src, norm_bits) int2; 8 gathers in flight.

template <bool RELU>
__global__ __launch_bounds__(256) void k_agg(const __half* __restrict__ H, const int* __restrict__ rowptr,
                                             const int* __restrict__ cnt, const int2* __restrict__ csr,
                                             const float* __restrict__ dinv, const float* __restrict__ bias,
                                             float* __restrict__ out, int n) {
    const int lane  = threadIdx.x & 63;
    const int wave0 = (int)((blockIdx.x * 256 + threadIdx.x) >> 6);
    const int nwave = (int)((gridDim.x * 256) >> 6);
    const unsigned int* __restrict__ Hu = (const unsigned int*)H;   // 64 uints per row
    const float2 b = *(const float2*)&bias[lane * 2];

    for (int node = wave0; node < n; node += nwave) {
        float dv = dinv[node];
        unsigned int hu = Hu[(size_t)node * 64 + lane];
        float2 h = __half22float2(*(__half2*)&hu);
        float w0 = dv * dv;
        float ax = fmaf(w0, h.x, b.x);
        float ay = fmaf(w0, h.y, b.y);

        const int c0 = rowptr[node];
        const int cn = cnt[node];
        #pragma unroll 2
        for (int e8 = 0; e8 < cn; e8 += 8) {
            const int4* q = (const int4*)(csr + c0 + e8);   // 16B-aligned
            int4 q0 = q[0], q1 = q[1], q2 = q[2], q3 = q[3];
            unsigned int u0 = Hu[(size_t)q0.x * 64 + lane];
            unsigned int u1 = Hu[(size_t)q0.z * 64 + lane];
            unsigned int u2 = Hu[(size_t)q1.x * 64 + lane];
            unsigned int u3 = Hu[(size_t)q1.z * 64 + lane];
            unsigned int u4 = Hu[(size_t)q2.x * 64 + lane];
            unsigned int u5 = Hu[(size_t)q2.z * 64 + lane];
            unsigned int u6 = Hu[(size_t)q3.x * 64 + lane];
            unsigned int u7 = Hu[(size_t)q3.z * 64 + lane];
            float2 g0 = __half22float2(*(__half2*)&u0);
            float2 g1 = __half22float2(*(__half2*)&u1);
            float2 g2 = __half22float2(*(__half2*)&u2);
            float2 g3 = __half22float2(*(__half2*)&u3);
            float2 g4 = __half22float2(*(__half2*)&u4);
            float2 g5 = __half22float2(*(__half2*)&u5);
            float2 g6 = __half22float2(*(__half2*)&u6);
            float2 g7 = __half22float2(*(__half2*)&u7);
            float w0_ = __int_as_float(q0.y), w1_ = __int_as_float(q0.w);
            float w2_ = __int_as_float(q1.y), w3_ = __int_as_float(q1.w);
            float w4_ = __int_as_float(q2.y), w5_ = __int_as_float(q2.w);
            float w6_ = __int_as_float(q3.y), w7_ = __int_as_float(q3.w);
            ax = fmaf(w0_, g0.x, ax); ay = fmaf(w0_, g0.y, ay);
            ax = fmaf(w1_, g1.x, ax); ay = fmaf(w1_, g1.y, ay);
            ax = fmaf(w2_, g2.x, ax); ay = fmaf(w2_, g2.y, ay);
            ax = fmaf(w3_, g3.x, ax); ay = fmaf(w3_, g3.y, ay);
            ax = fmaf(w4_, g4.x, ax); ay = fmaf(w4_, g4.y, ay);
            ax = fmaf(w5_, g5.x, ax); ay = fmaf(w5_, g5.y, ay);
            ax = fmaf(w6_, g6.x, ax); ay = fmaf(w6_, g6.y, ay);
            ax = fmaf(w7_, g7.x, ax); ay = fmaf(w7_, g7.y, ay);
        }

        if (RELU) {
            ax = fmaxf(ax, 0.f);
            ay = fmaxf(ay, 0.f);
        }
        *(float2*)&out[(size_t)node * 128 + lane * 2] = make_float2(ax, ay);
    }
}

// ---------------- launch ----------------

extern "C" void kernel_launch(void* const* d_in, const int* in_sizes, int n_in,
                              void* d_out, int out_size, void* d_ws, size_t ws_size,
                              hipStream_t stream) {
    const float* x  = (const float*)d_in[0];
    const int*   ei = (const int*)d_in[1];
    const float* W1 = (const float*)d_in[2];
    const float* b1 = (const float*)d_in[3];
    const float* W2 = (const float*)d_in[4];
    const float* b2 = (const float*)d_in[5];
    const float* W3 = (const float*)d_in[6];
    const float* b3 = (const float*)d_in[7];
    float* out = (float*)d_out;

    const int N = N_NODES, E = N_EDGES;
    const int EP = E + 7 * N + 64;   // padded CSR capacity
    const int* src = ei;       // edge_index[0]
    const int* dst = ei + E;   // edge_index[1]

    char* w = (char*)d_ws;
    auto alloc = [&](size_t bytes) -> void* {
        void* p = (void*)w;
        w += (bytes + 255) & ~(size_t)255;
        return p;
    };
    int*      cnt    = (int*)alloc((size_t)N * 4);
    int*      excl   = (int*)alloc((size_t)N * 4);
    int*      bsum   = (int*)alloc(4096);
    int*      rowptr = (int*)alloc((size_t)N * 4);
    int*      fill   = (int*)alloc((size_t)N * 4);
    float*    dinv   = (float*)alloc((size_t)N * 4);
    int2*     csr    = (int2*)alloc((size_t)EP * 8);
    _Float16* Ph     = (_Float16*)alloc((size_t)N * 128 * 2);   // fp16 activations
    _Float16* WTh    = (_Float16*)alloc((size_t)128 * 256 * 2); // split weights (max K=256)
    _Float16* WTl    = (_Float16*)alloc((size_t)128 * 256 * 2);
    float*    Q      = out;  // f32 ping-pong through d_out; rewritten by final layer

    const int nbN = (N + 255) / 256;
    const int nbE = (E + 255) / 256;
    const int nbP = (EP + 255) / 256;

    // CSR build (8-padded segments, zero-filled padding)
    k_zero_int<<<nbN, 256, 0, stream>>>(cnt, N);
    k_count<<<nbE, 256, 0, stream>>>(dst, cnt, E);
    k_scan_block<<<nbN, 256, 0, stream>>>(cnt, excl, bsum, N);
    k_scan_partials<<<1, 512, 0, stream>>>(bsum, nbN);
    k_finalize<<<nbN, 256, 0, stream>>>(excl, bsum, cnt, rowptr, fill, dinv, N);
    k_zero_csr<<<nbP, 256, 0, stream>>>(csr, EP);
    k_fill_edges<<<nbE, 256, 0, stream>>>(src, dst, dinv, fill, csr, E);

    const int gemm_grid = (N + 63) / 64;   // 1563
    const int agg_grid  = 2048;

    // layer 1
    k_wsplit<<<(256 * 128 + 255) / 256, 256, 0, stream>>>(W1, WTh, WTl, 256);
    k_gemm_mfma<256><<<gemm_grid, 256, 0, stream>>>(x, WTh, WTl, Ph, N);
    k_agg<true><<<agg_grid, 256, 0, stream>>>((const __half*)Ph, rowptr, cnt, csr, dinv, b1, Q, N);
    // layer 2
    k_wsplit<<<(128 * 128 + 255) / 256, 256, 0, stream>>>(W2, WTh, WTl, 128);
    k_gemm_mfma<128><<<gemm_grid, 256, 0, stream>>>(Q, WTh, WTl, Ph, N);
    k_agg<true><<<agg_grid, 256, 0, stream>>>((const __half*)Ph, rowptr, cnt, csr, dinv, b2, Q, N);
    // layer 3
    k_wsplit<<<(128 * 128 + 255) / 256, 256, 0, stream>>>(W3, WTh, WTl, 128);
    k_gemm_mfma<128><<<gemm_grid, 256, 0, stream>>>(Q, WTh, WTl, Ph, N);
    k_agg<false><<<agg_grid, 256, 0, stream>>>((const __half*)Ph, rowptr, cnt, csr, dinv, b3, out, N);
}

// Round 6
// 470.059 us; speedup vs baseline: 1.2932x; 1.2932x over previous
//
#include <hip/hip_runtime.h>
#include <hip/hip_fp16.h>
#include <math.h>

// GCN 3-layer: h = relu(Agg(x@W1)+b1); h = relu(Agg(h@W2)+b2); out = Agg(h@W3)+b3
// Agg[i] = dinv[i]^2 * g[i] + sum_{e: dst=i} dinv[src]*dinv[i] * g[src]
// dinv = rsqrt(in_deg + 1)
// GEMMs: MFMA, fp16 hi/lo split (XhWh + XlWh + XhWl) for f32-level accuracy.
// W pre-packed in per-fragment order so B-loads are coalesced; K-loop fully
// unrolled so the scheduler pipelines loads under MFMAs.
// Activations stored fp16 for the gather phase; aggregation accumulates f32.

#define N_NODES 100000
#define N_EDGES 1600000

typedef _Float16 f16x8 __attribute__((ext_vector_type(8)));
typedef float    f32x4 __attribute__((ext_vector_type(4)));

// ---------------- preprocessing ----------------

__global__ __launch_bounds__(256) void k_zero_int(int* __restrict__ p, int n) {
    int i = blockIdx.x * 256 + threadIdx.x;
    if (i < n) p[i] = 0;
}

__global__ __launch_bounds__(256) void k_count(const int* __restrict__ dst, int* __restrict__ cnt, int E) {
    int e = blockIdx.x * 256 + threadIdx.x;
    if (e < E) atomicAdd(&cnt[dst[e]], 1);
}

// per-256-block exclusive scan (over 8-padded counts) + block sums
__global__ __launch_bounds__(256) void k_scan_block(const int* __restrict__ cnt, int* __restrict__ excl,
                                                    int* __restrict__ bsum, int n) {
    __shared__ int s[256];
    int i = blockIdx.x * 256 + threadIdx.x;
    int v = (i < n) ? ((cnt[i] + 7) & ~7) : 0;   // padded segment length
    s[threadIdx.x] = v;
    __syncthreads();
    #pragma unroll
    for (int off = 1; off < 256; off <<= 1) {
        int t = (threadIdx.x >= (unsigned)off) ? s[threadIdx.x - off] : 0;
        __syncthreads();
        s[threadIdx.x] += t;
        __syncthreads();
    }
    if (i < n) excl[i] = s[threadIdx.x] - v;
    if (threadIdx.x == 255) bsum[blockIdx.x] = s[255];
}

// single-block exclusive scan over block sums (nb <= 512)
__global__ __launch_bounds__(512) void k_scan_partials(int* __restrict__ bsum, int nb) {
    __shared__ int s[512];
    int tid = threadIdx.x;
    int v = (tid < nb) ? bsum[tid] : 0;
    s[tid] = v;
    __syncthreads();
    #pragma unroll
    for (int off = 1; off < 512; off <<= 1) {
        int t = (tid >= (unsigned)off) ? s[tid - off] : 0;
        __syncthreads();
        s[tid] += t;
        __syncthreads();
    }
    if (tid < nb) bsum[tid] = s[tid] - v;   // exclusive
}

__global__ __launch_bounds__(256) void k_finalize(const int* __restrict__ excl, const int* __restrict__ bsum,
                                                  const int* __restrict__ cnt, int* __restrict__ rowptr,
                                                  int* __restrict__ fill, float* __restrict__ dinv, int n) {
    int i = blockIdx.x * 256 + threadIdx.x;
    if (i < n) {
        int rp = excl[i] + bsum[i >> 8];
        rowptr[i] = rp;     // 8-aligned
        fill[i]   = rp;
        dinv[i]   = rsqrtf((float)(cnt[i] + 1));
    }
}

__global__ __launch_bounds__(256) void k_zero_csr(int2* __restrict__ csr, int n) {
    int i = blockIdx.x * 256 + threadIdx.x;
    if (i < n) csr[i] = make_int2(0, 0);
}

__global__ __launch_bounds__(256) void k_fill_edges(const int* __restrict__ src, const int* __restrict__ dst,
                                                    const float* __restrict__ dinv, int* __restrict__ fill,
                                                    int2* __restrict__ csr, int E) {
    int e = blockIdx.x * 256 + threadIdx.x;
    if (e < E) {
        int s = src[e], d = dst[e];
        int p = atomicAdd(&fill[d], 1);
        csr[p] = make_int2(s, __float_as_int(dinv[s] * dinv[d]));
    }
}

// W pack: fragment-order layout so GEMM B-loads are lane-contiguous.
// Wpk[((c*8+tc)*64 + lane)*8 + i] = fp16(W[k][col]), col=tc*16+(lane&15),
// k=c*32+(lane>>4)*8+i. Lo residual at offset K*128.
__global__ __launch_bounds__(256) void k_wpack(const float* __restrict__ W, _Float16* __restrict__ Wpk, int K) {
    int j = blockIdx.x * 256 + threadIdx.x;
    if (j < K * 128) {
        int i  = j & 7;
        int l  = (j >> 3) & 63;
        int tc = (j >> 9) & 7;
        int c  = j >> 12;
        int col = tc * 16 + (l & 15);
        int k   = c * 32 + (l >> 4) * 8 + i;
        float w = W[(size_t)k * 128 + col];
        _Float16 h = (_Float16)w;
        Wpk[j] = h;
        Wpk[(size_t)K * 128 + j] = (_Float16)(w - (float)h);
    }
}

// ---------------- MFMA GEMM: Y[n,128] = X[n,K] @ W[K,128], fp16 out ----------------
// 4 waves/block, each wave owns 16 rows x 128 cols. No LDS, no barriers.
// A: f32 X rows split to fp16 hi/lo in registers. B: fragment-packed Wpk,
// each load = 64 lanes x 16B contiguous (coalesced, L2-resident).
// Fragment maps (guide §3, m89-verified): A row=lane&15, k=(lane>>4)*8+i;
// B col=lane&15, same k; D col=lane&15, row=(lane>>4)*4+reg.

template <int K>
__global__ __launch_bounds__(256, 3) void k_gemm_mfma(const float* __restrict__ X,
                                                      const _Float16* __restrict__ Wpk,
                                                      _Float16* __restrict__ Y, int n) {
    const int t    = threadIdx.x;
    const int wave = t >> 6;
    const int lane = t & 63;
    const int lrow = lane & 15;
    const int kgrp = lane >> 4;          // 0..3
    const int row0 = blockIdx.x * 64 + wave * 16;
    const int arow = row0 + lrow;
    const bool rok = arow < n;
    const float* __restrict__ xrow = X + (size_t)arow * K;
    const _Float16* __restrict__ Wlo = Wpk + (size_t)K * 128;

    f32x4 acc[8];
    #pragma unroll
    for (int i = 0; i < 8; ++i) acc[i] = (f32x4){0.f, 0.f, 0.f, 0.f};

    #pragma unroll
    for (int c = 0; c < K / 32; ++c) {
        const int k0 = c * 32 + kgrp * 8;
        float4 x0 = make_float4(0.f, 0.f, 0.f, 0.f);
        float4 x1 = make_float4(0.f, 0.f, 0.f, 0.f);
        if (rok) {
            x0 = *(const float4*)&xrow[k0];
            x1 = *(const float4*)&xrow[k0 + 4];
        }
        float xs[8] = {x0.x, x0.y, x0.z, x0.w, x1.x, x1.y, x1.z, x1.w};
        f16x8 ah, al;
        #pragma unroll
        for (int i = 0; i < 8; ++i) {
            _Float16 h = (_Float16)xs[i];
            ah[i] = h;
            al[i] = (_Float16)(xs[i] - (float)h);
        }
        const size_t wb = ((size_t)(c * 8) * 64 + lane) * 8;
        #pragma unroll
        for (int tc = 0; tc < 8; ++tc) {
            f16x8 bh = *(const f16x8*)(Wpk + wb + (size_t)tc * 512);
            f16x8 bl = *(const f16x8*)(Wlo + wb + (size_t)tc * 512);
            acc[tc] = __builtin_amdgcn_mfma_f32_16x16x32_f16(ah, bh, acc[tc], 0, 0, 0);
            acc[tc] = __builtin_amdgcn_mfma_f32_16x16x32_f16(al, bh, acc[tc], 0, 0, 0);
            acc[tc] = __builtin_amdgcn_mfma_f32_16x16x32_f16(ah, bl, acc[tc], 0, 0, 0);
        }
    }

    #pragma unroll
    for (int r = 0; r < 4; ++r) {
        int grow = row0 + kgrp * 4 + r;
        if (grow < n) {
            _Float16* yr = Y + (size_t)grow * 128 + lrow;
            #pragma unroll
            for (int tc = 0; tc < 8; ++tc) yr[tc * 16] = (_Float16)acc[tc][r];
        }
    }
}

// ---------------- aggregation (+ bias, + optional relu) ----------------
// one wave per node, grid-stride; lane holds 2 features (uint = 2 halves).
// CSR 8-padded, interleaved (src, norm_bits) int2; 8 gathers in flight.

template <bool RELU>
__global__ __launch_bounds__(256) void k_agg(const __half* __restrict__ H, const int* __restrict__ rowptr,
                                             const int* __restrict__ cnt, const int2* __restrict__ csr,
                                             const float* __restrict__ dinv, const float* __restrict__ bias,
                                             float* __restrict__ out, int n) {
    const int lane  = threadIdx.x & 63;
    const int wave0 = (int)((blockIdx.x * 256 + threadIdx.x) >> 6);
    const int nwave = (int)((gridDim.x * 256) >> 6);
    const unsigned int* __restrict__ Hu = (const unsigned int*)H;   // 64 uints per row
    const float2 b = *(const float2*)&bias[lane * 2];

    for (int node = wave0; node < n; node += nwave) {
        float dv = dinv[node];
        unsigned int hu = Hu[(size_t)node * 64 + lane];
        float2 h = __half22float2(*(__half2*)&hu);
        float w0 = dv * dv;
        float ax = fmaf(w0, h.x, b.x);
        float ay = fmaf(w0, h.y, b.y);

        const int c0 = rowptr[node];
        const int cn = cnt[node];
        #pragma unroll 2
        for (int e8 = 0; e8 < cn; e8 += 8) {
            const int4* q = (const int4*)(csr + c0 + e8);   // 16B-aligned
            int4 q0 = q[0], q1 = q[1], q2 = q[2], q3 = q[3];
            unsigned int u0 = Hu[(size_t)q0.x * 64 + lane];
            unsigned int u1 = Hu[(size_t)q0.z * 64 + lane];
            unsigned int u2 = Hu[(size_t)q1.x * 64 + lane];
            unsigned int u3 = Hu[(size_t)q1.z * 64 + lane];
            unsigned int u4 = Hu[(size_t)q2.x * 64 + lane];
            unsigned int u5 = Hu[(size_t)q2.z * 64 + lane];
            unsigned int u6 = Hu[(size_t)q3.x * 64 + lane];
            unsigned int u7 = Hu[(size_t)q3.z * 64 + lane];
            float2 g0 = __half22float2(*(__half2*)&u0);
            float2 g1 = __half22float2(*(__half2*)&u1);
            float2 g2 = __half22float2(*(__half2*)&u2);
            float2 g3 = __half22float2(*(__half2*)&u3);
            float2 g4 = __half22float2(*(__half2*)&u4);
            float2 g5 = __half22float2(*(__half2*)&u5);
            float2 g6 = __half22float2(*(__half2*)&u6);
            float2 g7 = __half22float2(*(__half2*)&u7);
            float w0_ = __int_as_float(q0.y), w1_ = __int_as_float(q0.w);
            float w2_ = __int_as_float(q1.y), w3_ = __int_as_float(q1.w);
            float w4_ = __int_as_float(q2.y), w5_ = __int_as_float(q2.w);
            float w6_ = __int_as_float(q3.y), w7_ = __int_as_float(q3.w);
            ax = fmaf(w0_, g0.x, ax); ay = fmaf(w0_, g0.y, ay);
            ax = fmaf(w1_, g1.x, ax); ay = fmaf(w1_, g1.y, ay);
            ax = fmaf(w2_, g2.x, ax); ay = fmaf(w2_, g2.y, ay);
            ax = fmaf(w3_, g3.x, ax); ay = fmaf(w3_, g3.y, ay);
            ax = fmaf(w4_, g4.x, ax); ay = fmaf(w4_, g4.y, ay);
            ax = fmaf(w5_, g5.x, ax); ay = fmaf(w5_, g5.y, ay);
            ax = fmaf(w6_, g6.x, ax); ay = fmaf(w6_, g6.y, ay);
            ax = fmaf(w7_, g7.x, ax); ay = fmaf(w7_, g7.y, ay);
        }

        if (RELU) {
            ax = fmaxf(ax, 0.f);
            ay = fmaxf(ay, 0.f);
        }
        *(float2*)&out[(size_t)node * 128 + lane * 2] = make_float2(ax, ay);
    }
}

// ---------------- launch ----------------

extern "C" void kernel_launch(void* const* d_in, const int* in_sizes, int n_in,
                              void* d_out, int out_size, void* d_ws, size_t ws_size,
                              hipStream_t stream) {
    const float* x  = (const float*)d_in[0];
    const int*   ei = (const int*)d_in[1];
    const float* W1 = (const float*)d_in[2];
    const float* b1 = (const float*)d_in[3];
    const float* W2 = (const float*)d_in[4];
    const float* b2 = (const float*)d_in[5];
    const float* W3 = (const float*)d_in[6];
    const float* b3 = (const float*)d_in[7];
    float* out = (float*)d_out;

    const int N = N_NODES, E = N_EDGES;
    const int EP = E + 7 * N + 64;   // padded CSR capacity
    const int* src = ei;       // edge_index[0]
    const int* dst = ei + E;   // edge_index[1]

    char* w = (char*)d_ws;
    auto alloc = [&](size_t bytes) -> void* {
        void* p = (void*)w;
        w += (bytes + 255) & ~(size_t)255;
        return p;
    };
    int*      cnt    = (int*)alloc((size_t)N * 4);
    int*      excl   = (int*)alloc((size_t)N * 4);
    int*      bsum   = (int*)alloc(4096);
    int*      rowptr = (int*)alloc((size_t)N * 4);
    int*      fill   = (int*)alloc((size_t)N * 4);
    float*    dinv   = (float*)alloc((size_t)N * 4);
    int2*     csr    = (int2*)alloc((size_t)EP * 8);
    _Float16* Ph     = (_Float16*)alloc((size_t)N * 128 * 2);     // fp16 activations
    _Float16* Wpk    = (_Float16*)alloc((size_t)2 * 256 * 128 * 2); // packed split weights (max K=256)
    float*    Q      = out;  // f32 ping-pong through d_out; rewritten by final layer

    const int nbN = (N + 255) / 256;
    const int nbE = (E + 255) / 256;
    const int nbP = (EP + 255) / 256;

    // CSR build (8-padded segments, zero-filled padding)
    k_zero_int<<<nbN, 256, 0, stream>>>(cnt, N);
    k_count<<<nbE, 256, 0, stream>>>(dst, cnt, E);
    k_scan_block<<<nbN, 256, 0, stream>>>(cnt, excl, bsum, N);
    k_scan_partials<<<1, 512, 0, stream>>>(bsum, nbN);
    k_finalize<<<nbN, 256, 0, stream>>>(excl, bsum, cnt, rowptr, fill, dinv, N);
    k_zero_csr<<<nbP, 256, 0, stream>>>(csr, EP);
    k_fill_edges<<<nbE, 256, 0, stream>>>(src, dst, dinv, fill, csr, E);

    const int gemm_grid = (N + 63) / 64;   // 1563
    const int agg_grid  = 2048;

    // layer 1
    k_wpack<<<(256 * 128 + 255) / 256, 256, 0, stream>>>(W1, Wpk, 256);
    k_gemm_mfma<256><<<gemm_grid, 256, 0, stream>>>(x, Wpk, Ph, N);
    k_agg<true><<<agg_grid, 256, 0, stream>>>((const __half*)Ph, rowptr, cnt, csr, dinv, b1, Q, N);
    // layer 2
    k_wpack<<<(128 * 128 + 255) / 256, 256, 0, stream>>>(W2, Wpk, 128);
    k_gemm_mfma<128><<<gemm_grid, 256, 0, stream>>>(Q, Wpk, Ph, N);
    k_agg<true><<<agg_grid, 256, 0, stream>>>((const __half*)Ph, rowptr, cnt, csr, dinv, b2, Q, N);
    // layer 3
    k_wpack<<<(128 * 128 + 255) / 256, 256, 0, stream>>>(W3, Wpk, 128);
    k_gemm_mfma<128><<<gemm_grid, 256, 0, stream>>>(Q, Wpk, Ph, N);
    k_agg<false><<<agg_grid, 256, 0, stream>>>((const __half*)Ph, rowptr, cnt, csr, dinv, b3, out, N);
}